// Round 8
// baseline (122.222 us; speedup 1.0000x reference)
//
#include <hip/hip_runtime.h>
#include <hip/hip_bf16.h>

typedef unsigned short u16;
typedef __bf16 bf16x8 __attribute__((ext_vector_type(8)));
typedef float f32x4 __attribute__((ext_vector_type(4)));
typedef u16 u16x8 __attribute__((ext_vector_type(8)));
typedef u16 u16x4 __attribute__((ext_vector_type(4)));

__device__ __forceinline__ u16 f2bf(float f) {
    unsigned u = __builtin_bit_cast(unsigned, f);
    unsigned r = u + 0x7FFFu + ((u >> 16) & 1u);
    return (u16)(r >> 16);
}
__device__ __forceinline__ float bf2f(u16 h) {
    return __builtin_bit_cast(float, (unsigned)h << 16);
}
__device__ __forceinline__ unsigned cvt_pk_bf16(float lo, float hi) {
    unsigned r;
    asm("v_cvt_pk_bf16_f32 %0, %1, %2" : "=v"(r) : "v"(lo), "v"(hi));
    return r;
}
__device__ __forceinline__ void gload16(const void* g, void* l) {
    __builtin_amdgcn_global_load_lds((const __attribute__((address_space(1))) void*)g,
                                     (__attribute__((address_space(3))) void*)l, 16, 0, 0);
}

// ---------- fused fp32 -> bf16 convert of x | Wqkv | Wo into contiguous ws ----------
__global__ __launch_bounds__(256) void cvt_all(const float* __restrict__ x,
                                               const float* __restrict__ wqkv,
                                               const float* __restrict__ wo,
                                               u16* __restrict__ dst, int n0, int n1) {
    int i = (blockIdx.x * 256 + threadIdx.x) * 4;
    const float* src;
    if (i < n0)            src = x + i;
    else if (i < n0 + n1)  src = wqkv + (i - n0);
    else                   src = wo + (i - n0 - n1);
    float4 v = *(const float4*)src;
    u16x4 o;
    o[0] = f2bf(v.x); o[1] = f2bf(v.y); o[2] = f2bf(v.z); o[3] = f2bf(v.w);
    *(u16x4*)(dst + i) = o;
}

// ------------- deep-pipelined bf16 GEMM: C[M][N] = A[M][K] * Bt[N][K]^T -------------
// BK=64, double-buffered LDS, counted vmcnt (loads for tile t+1 issued at start of
// tile t -> full-tile lead), XOR-swizzled tiles via pre-swizzled source.
// PHASED: split each K-tile into 4 quadrant phases (ks x M-half), each
// {ds_read; barrier; setprio(1); MFMA cluster; setprio(0); barrier} - T3-style
// role-split so waves alternate LDS-read and MFMA clusters.
template <int BM, int BN, int WR, int WC, bool OUT_BF16, bool PHASED>
__global__ __launch_bounds__(WR * WC * 64, 2) void gemm_pipe(const u16* __restrict__ A,
                                                             const u16* __restrict__ Bt,
                                                             void* __restrict__ C,
                                                             int M, int N, int K) {
    constexpr int NW = WR * WC;
    constexpr int MR = BM / WR / 16, NR = BN / WC / 16;
    constexpr int MH = MR / 2;                    // frags per M-half phase
    constexpr int CA = BM / 8, CB = BN / 8;       // 1KB staging chunks (8 rows x 128B)
    constexpr int CAW = CA / NW, CBW = CB / NW;   // chunks per wave
    constexpr int NLD = CAW + CBW;                // gloads per thread per tile

    __shared__ u16 lA[2][BM * 64];
    __shared__ u16 lB[2][BN * 64];

    const int tid = threadIdx.x, lane = tid & 63, w = tid >> 6;
    const int wr = w / WC, wc = w % WC;
    const int lr = lane & 15, lg = lane >> 4;
    const int sw = (lr & 7) << 4;                 // read-side swizzle (bytes)
    const int bm = blockIdx.x * BM, bn = blockIdx.y * BN;
    const int jr = lane >> 3;                     // row within 8-row chunk
    const int scbe = ((((lane & 7) * 16) ^ (jr << 4)) >> 1); // pre-swizzled src col (elems)
    const int nTk = K >> 6;

    f32x4 acc[MR][NR];
#pragma unroll
    for (int i = 0; i < MR; i++)
#pragma unroll
        for (int j = 0; j < NR; j++) acc[i][j] = (f32x4){0.f, 0.f, 0.f, 0.f};

    const u16* aSrc = A + (size_t)bm * K + scbe;
    const u16* bSrc = Bt + (size_t)bn * K + scbe;

#define STAGEP(p_, t_)                                                           \
    {                                                                            \
        _Pragma("unroll") for (int q = 0; q < CAW; q++) {                        \
            int ck = w * CAW + q;                                                \
            gload16(aSrc + (size_t)(ck * 8 + jr) * K + (t_) * 64,                \
                    &lA[p_][ck * 512]);                                          \
        }                                                                        \
        _Pragma("unroll") for (int q = 0; q < CBW; q++) {                        \
            int ck = w * CBW + q;                                                \
            gload16(bSrc + (size_t)(ck * 8 + jr) * K + (t_) * 64,                \
                    &lB[p_][ck * 512]);                                          \
        }                                                                        \
    }

    STAGEP(0, 0);

    for (int t = 0; t < nTk; t++) {
        const int p = t & 1;
        if (t + 1 < nTk) {
            STAGEP(p ^ 1, t + 1);
            if constexpr (NLD == 8)
                asm volatile("s_waitcnt vmcnt(8)" ::: "memory");
            else if constexpr (NLD == 7)
                asm volatile("s_waitcnt vmcnt(7)" ::: "memory");
            else
                asm volatile("s_waitcnt vmcnt(0)" ::: "memory");
        } else {
            asm volatile("s_waitcnt vmcnt(0)" ::: "memory");
        }
        __builtin_amdgcn_s_barrier();
        __builtin_amdgcn_sched_barrier(0);        // keep ds_reads below the barrier

        const char* pa = (const char*)&lA[p][0] + (size_t)(wr * MR * 16) * 128;
        const char* pb = (const char*)&lB[p][0] + (size_t)(wc * NR * 16) * 128;
#pragma unroll
        for (int ks = 0; ks < 2; ks++) {
            bf16x8 bfr[NR];
#pragma unroll
            for (int mh = 0; mh < 2; mh++) {
                if (mh == 0) {
#pragma unroll
                    for (int j = 0; j < NR; j++)
                        bfr[j] = *(const bf16x8*)(pb + (j * 16 + lr) * 128 +
                                                  ((ks * 64 + lg * 16) ^ sw));
                }
                bf16x8 af[MH];
#pragma unroll
                for (int i = 0; i < MH; i++)
                    af[i] = *(const bf16x8*)(pa + ((mh * MH + i) * 16 + lr) * 128 +
                                             ((ks * 64 + lg * 16) ^ sw));
                if (PHASED) __builtin_amdgcn_s_barrier();
                __builtin_amdgcn_s_setprio(1);
#pragma unroll
                for (int i = 0; i < MH; i++)
#pragma unroll
                    for (int j = 0; j < NR; j++)
                        acc[mh * MH + i][j] = __builtin_amdgcn_mfma_f32_16x16x32_bf16(
                            af[i], bfr[j], acc[mh * MH + i][j], 0, 0, 0);
                __builtin_amdgcn_s_setprio(0);
                if (PHASED) __builtin_amdgcn_s_barrier();
            }
        }
        if (!PHASED) __builtin_amdgcn_s_barrier();
    }
#undef STAGEP

    const int row0 = bm + wr * MR * 16, col0 = bn + wc * NR * 16;
#pragma unroll
    for (int i = 0; i < MR; i++)
#pragma unroll
        for (int j = 0; j < NR; j++)
#pragma unroll
            for (int r = 0; r < 4; r++) {
                int m = row0 + i * 16 + lg * 4 + r;
                int n = col0 + j * 16 + lr;
                float v = acc[i][j][r];
                if (OUT_BF16)
                    ((u16*)C)[(size_t)m * N + n] = f2bf(v);
                else
                    ((float*)C)[(size_t)m * N + n] = v;
            }
}

// ---------- fused RoPE+RMSNorm (blocks [0,nbRope)) + V transpose (rest) ----------
__global__ __launch_bounds__(256) void rope_trans(u16* __restrict__ qkv,
                                                  const float* __restrict__ cosc,
                                                  const float* __restrict__ sinc,
                                                  const int* __restrict__ pos_ids,
                                                  u16* __restrict__ vT, int S, int nbRope) {
    __shared__ u16 lt[64][72];
    const int bid = blockIdx.x;
    const int tid = threadIdx.x;
    if (bid < nbRope) {
        int idx = bid * 4 + (tid >> 6);
        int lane = tid & 63;
        int token = idx >> 5;
        int rem = idx & 31;
        int which = rem >> 4;   // 0=q, 1=k
        int h = rem & 15;
        u16* p = qkv + (size_t)token * 3072 + which * 1024 + h * 64;
        float x = bf2f(p[lane]);
        float xp = __shfl_xor(x, 32);
        int pos = pos_ids[token];
        int j = lane & 31;
        float c = cosc[pos * 32 + j], s = sinc[pos * 32 + j];
        float y = (lane < 32) ? (x * c + xp * s) : (x * c - xp * s);
        float ss = y * y;
#pragma unroll
        for (int m = 1; m < 64; m <<= 1) ss += __shfl_xor(ss, m);
        float r = rsqrtf(ss * (1.0f / 64.0f) + 1.1920929e-07f);
        p[lane] = f2bf(y * r);
    } else {
        int t = bid - nbRope;
        int nsc = S >> 6;
        int bh = t / nsc;
        int b = bh >> 4, h = bh & 15;
        int s0 = (t - bh * nsc) * 64;
        {
            int s = tid >> 2, dp = (tid & 3) * 16;
            const u16* src = qkv + (size_t)(b * S + s0 + s) * 3072 + 2048 + h * 64 + dp;
            u16x8 v0 = *(const u16x8*)src;
            u16x8 v1 = *(const u16x8*)(src + 8);
#pragma unroll
            for (int i = 0; i < 8; i++) lt[s][dp + i] = v0[i];
#pragma unroll
            for (int i = 0; i < 8; i++) lt[s][dp + 8 + i] = v1[i];
        }
        __syncthreads();
        {
            int d = tid >> 2, sp = (tid & 3) * 16;
            u16x8 o0, o1;
#pragma unroll
            for (int i = 0; i < 8; i++) o0[i] = lt[sp + i][d];
#pragma unroll
            for (int i = 0; i < 8; i++) o1[i] = lt[sp + 8 + i][d];
            u16* dst = vT + ((size_t)bh * 64 + d) * S + s0 + sp;
            *(u16x8*)dst = o0;
            *(u16x8*)(dst + 8) = o1;
        }
    }
}

// ---------------- causal flash attention, balanced-pair + dbuf, base-2 ----------------
// grid (B*H, S/128). Block p handles q-tiles {p, nq-1-p} sequentially -> every
// block does exactly nq+1 kv-steps. Swapped QK^T, lane-local softmax.
__global__ __launch_bounds__(256) void attn_fwd(const u16* __restrict__ qkv,
                                                const u16* __restrict__ vT,
                                                u16* __restrict__ out, int S) {
    const int bh = blockIdx.x, b = bh >> 4, h = bh & 15;
    const int tid = threadIdx.x, lane = tid & 63, w = tid >> 6;
    const int lr = lane & 15, lg = lane >> 4;
    const int sw = (lr & 7) << 4;            // read-side XOR swizzle (byte)

    const int nq = S >> 6;
    const int i1 = blockIdx.y;               // light tile
    const int i2 = (nq - 1) - i1;            // heavy tile
    const int n1 = i1 + 1, ntot = n1 + i2 + 1;

    __shared__ u16 lK[2][64 * 64];           // [kv][d], rows 128B, swizzled
    __shared__ u16 lVt[2][64 * 64];          // [d][kv], rows 128B, swizzled
    __shared__ u16 lP[4][16 * 64];           // per wave: P[q][k], swizzled

    const int jr = lane >> 3;                // row within chunk
    const int cbyte = (lane & 7) * 16;
    const int scb = cbyte ^ (jr << 4);       // pre-swizzled source byte col
    const int rowA = w * 16 + jr, rowB = rowA + 8;
    const u16* kSrc = qkv + 1024 + h * 64 + (scb >> 1);
    const u16* vSrc = vT + (size_t)bh * 64 * S + (scb >> 1);

#define STAGE(bufi, kv0_)                                                        \
    {                                                                            \
        const u16* kb = kSrc + (size_t)(b * S + (kv0_)) * 3072;                  \
        const u16* vb = vSrc + (kv0_);                                           \
        gload16(kb + (size_t)rowA * 3072, &lK[bufi][(w * 2) * 512]);             \
        gload16(kb + (size_t)rowB * 3072, &lK[bufi][(w * 2 + 1) * 512]);         \
        gload16(vb + (size_t)rowA * S, &lVt[bufi][(w * 2) * 512]);               \
        gload16(vb + (size_t)rowB * S, &lVt[bufi][(w * 2 + 1) * 512]);           \
    }

    bf16x8 bQ[2];
    f32x4 oT[4];
    float mrun, lrun;

    // Q pre-scaled by 1/sqrt(64)*log2(e): softmax fully in base-2 domain
#define LOADQ(tile_)                                                             \
    {                                                                            \
        const u16* qp = qkv + (size_t)(b * S + (tile_)*64 + w * 16 + lr) * 3072 + h * 64; \
        _Pragma("unroll") for (int hf = 0; hf < 2; hf++) {                       \
            u16x8 t = *(const u16x8*)(qp + hf * 32 + lg * 8);                    \
            bf16x8 a;                                                            \
            _Pragma("unroll") for (int i = 0; i < 8; i++)                        \
                a[i] = (__bf16)(bf2f(t[i]) * 0.18033688f);                       \
            bQ[hf] = a;                                                          \
        }                                                                        \
    }

    STAGE(0, 0);
    LOADQ(i1);
#pragma unroll
    for (int df = 0; df < 4; df++) oT[df] = (f32x4){0.f, 0.f, 0.f, 0.f};
    mrun = -3.0e38f; lrun = 0.f;
    __syncthreads();

    int buf = 0;
    for (int s = 0; s < ntot; s++) {
        const int tile = (s < n1) ? i1 : i2;
        const int kv0 = ((s < n1) ? s : s - n1) * 64;
        if (s + 1 < ntot) {
            int ns = s + 1;
            int nkv0 = ((ns < n1) ? ns : ns - n1) * 64;
            STAGE(buf ^ 1, nkv0);
        }
        const bool diag = (s == n1 - 1) || (s == ntot - 1);

        // ---- QK^T (swapped): S^T[kv][q] ----
        f32x4 st[4];
#pragma unroll
        for (int kf = 0; kf < 4; kf++) {
            const char* kb = (const char*)&lK[buf][0] + (kf * 16 + lr) * 128;
            bf16x8 k0 = *(const bf16x8*)(kb + ((lg * 16) ^ sw));
            bf16x8 k1 = *(const bf16x8*)(kb + ((64 + lg * 16) ^ sw));
            f32x4 z = (f32x4){0.f, 0.f, 0.f, 0.f};
            z = __builtin_amdgcn_mfma_f32_16x16x32_bf16(k0, bQ[0], z, 0, 0, 0);
            st[kf] = __builtin_amdgcn_mfma_f32_16x16x32_bf16(k1, bQ[1], z, 0, 0, 0);
        }

        // ---- mask (diagonal steps only) + lane-local online softmax (base 2) ----
        if (diag) {
            const int qg = tile * 64 + w * 16 + lr;
#pragma unroll
            for (int kf = 0; kf < 4; kf++)
#pragma unroll
                for (int r = 0; r < 4; r++) {
                    int kvg = kv0 + kf * 16 + lg * 4 + r;
                    if (kvg > qg) st[kf][r] = -3.0e38f;
                }
        }
        float mx = -3.0e38f;
#pragma unroll
        for (int kf = 0; kf < 4; kf++) {
            float mk = fmaxf(fmaxf(st[kf][0], st[kf][1]), fmaxf(st[kf][2], st[kf][3]));
            mx = fmaxf(mx, mk);
        }
        mx = fmaxf(mx, __shfl_xor(mx, 16));
        mx = fmaxf(mx, __shfl_xor(mx, 32));
        if (!__all(mx <= mrun + 11.54f)) {    // T13 defer-max (log2 domain)
            float mnew = fmaxf(mrun, mx);
            float alpha = exp2f(mrun - mnew);
            mrun = mnew;
            lrun *= alpha;
#pragma unroll
            for (int df = 0; df < 4; df++)
#pragma unroll
                for (int r = 0; r < 4; r++) oT[df][r] *= alpha;
        }
        float ps = 0.f;
#pragma unroll
        for (int kf = 0; kf < 4; kf++)
#pragma unroll
            for (int r = 0; r < 4; r++) {
                float p = exp2f(st[kf][r] - mrun);
                st[kf][r] = p;
                ps += p;
            }
        ps += __shfl_xor(ps, 16);
        ps += __shfl_xor(ps, 32);
        lrun += ps;

        // ---- P -> LDS (bf16, swizzled rows of 128B) ----
        {
            char* pb = (char*)&lP[w][0] + lr * 128;
#pragma unroll
            for (int kf = 0; kf < 4; kf++) {
                uint2 pk;
                pk.x = cvt_pk_bf16(st[kf][0], st[kf][1]);
                pk.y = cvt_pk_bf16(st[kf][2], st[kf][3]);
                *(uint2*)(pb + ((kf * 32 + lg * 8) ^ sw)) = pk;
            }
        }

        // ---- PV (swapped): O^T += Vt . P^T ----
#pragma unroll
        for (int kc = 0; kc < 2; kc++) {
            bf16x8 bp = *(const bf16x8*)((const char*)&lP[w][0] + lr * 128 +
                                         ((kc * 64 + lg * 16) ^ sw));
#pragma unroll
            for (int df = 0; df < 4; df++) {
                bf16x8 av = *(const bf16x8*)((const char*)&lVt[buf][0] +
                                             (df * 16 + lr) * 128 +
                                             ((kc * 64 + lg * 16) ^ sw));
                oT[df] = __builtin_amdgcn_mfma_f32_16x16x32_bf16(av, bp, oT[df], 0, 0, 0);
            }
        }

        if (diag) {
            float inv = 1.0f / lrun;
            u16* op = out + (size_t)(b * S + tile * 64 + w * 16 + lr) * 1024 +
                      h * 64 + lg * 4;
#pragma unroll
            for (int df = 0; df < 4; df++) {
                u16x4 o;
#pragma unroll
                for (int r = 0; r < 4; r++) o[r] = f2bf(oT[df][r] * inv);
                *(u16x4*)(op + df * 16) = o;
            }
            if (s != ntot - 1) {              // switch to heavy tile
                LOADQ(i2);
#pragma unroll
                for (int df = 0; df < 4; df++) oT[df] = (f32x4){0.f, 0.f, 0.f, 0.f};
                mrun = -3.0e38f; lrun = 0.f;
            }
        }
        __syncthreads();
        buf ^= 1;
    }
#undef STAGE
#undef LOADQ
}

extern "C" void kernel_launch(void* const* d_in, const int* in_sizes, int n_in,
                              void* d_out, int out_size, void* d_ws, size_t ws_size,
                              hipStream_t stream) {
    const float* x     = (const float*)d_in[0];
    const float* Wqkv  = (const float*)d_in[1];
    const float* Wo    = (const float*)d_in[2];
    const float* cosc  = (const float*)d_in[3];
    const float* sinc  = (const float*)d_in[4];
    const int* pos_ids = (const int*)d_in[6];

    const int E = 1024, H = 16;
    int S = in_sizes[3] / 32;       // cos_cache is S x 32
    int N = in_sizes[0] / E;
    int B = N / S;

    char* ws = (char*)d_ws;
    u16* xb    = (u16*)ws;                                          // N*E bf16 (reused as attn out)
    u16* wqkvb = (u16*)(ws + (size_t)N * E * 2);                    // 3E*E
    u16* wob   = (u16*)(ws + (size_t)N * E * 2 + (size_t)3 * E * E * 2);
    u16* qkvb  = (u16*)(ws + (size_t)N * E * 2 + (size_t)4 * E * E * 2);
    u16* vTb   = (u16*)(ws + (size_t)N * E * 2 + (size_t)4 * E * E * 2 + (size_t)N * 3 * E * 2);
    u16* aout  = xb;

    // one fused convert: dest segments xb|wqkvb|wob are contiguous in ws
    int n0 = N * E, n1 = 3 * E * E, n2 = E * E;
    cvt_all<<<(n0 + n1 + n2) / 1024, 256, 0, stream>>>(x, Wqkv, Wo, xb, n0, n1);

    // qkv GEMM: 256x192 tiles, 4-phase intra-tile schedule; grid 16x16 = 256 blocks
    gemm_pipe<256, 192, 2, 4, true, true><<<dim3(N / 256, 3 * E / 192), 512, 0, stream>>>(
        xb, wqkvb, qkvb, N, 3 * E, E);

    // fused RoPE+RMS (q,k) + V transpose
    int nbRope = N * 2 * H / 4;
    int nbTrans = B * H * (S / 64);
    rope_trans<<<nbRope + nbTrans, 256, 0, stream>>>(qkvb, cosc, sinc, pos_ids, vTb, S, nbRope);

    // attention: balanced-pair blocks, grid (B*H, S/128)
    attn_fwd<<<dim3(B * H, S / 128), 256, 0, stream>>>(qkvb, vTb, aout, S);

    // out GEMM: 128x128 tiles, non-phased (control); grid 32x8 = 256 blocks
    gemm_pipe<128, 128, 2, 2, false, false><<<dim3(N / 128, E / 128), 256, 0, stream>>>(
        aout, wob, d_out, N, E, E);
}

// Round 9
// 111.483 us; speedup vs baseline: 1.0963x; 1.0963x over previous
//
#include <hip/hip_runtime.h>
#include <hip/hip_bf16.h>

typedef unsigned short u16;
typedef __bf16 bf16x8 __attribute__((ext_vector_type(8)));
typedef float f32x4 __attribute__((ext_vector_type(4)));
typedef u16 u16x8 __attribute__((ext_vector_type(8)));
typedef u16 u16x4 __attribute__((ext_vector_type(4)));

__device__ __forceinline__ u16 f2bf(float f) {
    unsigned u = __builtin_bit_cast(unsigned, f);
    unsigned r = u + 0x7FFFu + ((u >> 16) & 1u);
    return (u16)(r >> 16);
}
__device__ __forceinline__ float bf2f(u16 h) {
    return __builtin_bit_cast(float, (unsigned)h << 16);
}
__device__ __forceinline__ unsigned cvt_pk_bf16(float lo, float hi) {
    unsigned r;
    asm("v_cvt_pk_bf16_f32 %0, %1, %2" : "=v"(r) : "v"(lo), "v"(hi));
    return r;
}
__device__ __forceinline__ void gload16(const void* g, void* l) {
    __builtin_amdgcn_global_load_lds((const __attribute__((address_space(1))) void*)g,
                                     (__attribute__((address_space(3))) void*)l, 16, 0, 0);
}

// ---------- fused fp32 -> bf16 convert of x | Wqkv | Wo into contiguous ws ----------
__global__ __launch_bounds__(256) void cvt_all(const float* __restrict__ x,
                                               const float* __restrict__ wqkv,
                                               const float* __restrict__ wo,
                                               u16* __restrict__ dst, int n0, int n1) {
    int i = (blockIdx.x * 256 + threadIdx.x) * 4;
    const float* src;
    if (i < n0)            src = x + i;
    else if (i < n0 + n1)  src = wqkv + (i - n0);
    else                   src = wo + (i - n0 - n1);
    float4 v = *(const float4*)src;
    u16x4 o;
    o[0] = f2bf(v.x); o[1] = f2bf(v.y); o[2] = f2bf(v.z); o[3] = f2bf(v.w);
    *(u16x4*)(dst + i) = o;
}

// ------------- deep-pipelined bf16 GEMM: C[M][N] = A[M][K] * Bt[N][K]^T -------------
// BK=64, double-buffered LDS, counted vmcnt (prefetch next tile in flight across
// compute), XOR-swizzled tiles (byte ^= (row&7)<<4) via pre-swizzled source.
// r5-proven configuration: single compute phase per K-tile, no mid-loop pins.
template <int BM, int BN, int WR, int WC, bool OUT_BF16>
__global__ __launch_bounds__(WR * WC * 64, 2) void gemm_pipe(const u16* __restrict__ A,
                                                             const u16* __restrict__ Bt,
                                                             void* __restrict__ C,
                                                             int M, int N, int K) {
    constexpr int NW = WR * WC;
    constexpr int MR = BM / WR / 16, NR = BN / WC / 16;
    constexpr int CA = BM / 8, CB = BN / 8;       // 1KB staging chunks (8 rows x 128B)
    constexpr int CAW = CA / NW, CBW = CB / NW;   // chunks per wave
    constexpr int NLD = CAW + CBW;                // gloads per thread per tile

    __shared__ u16 lA[2][BM * 64];
    __shared__ u16 lB[2][BN * 64];

    const int tid = threadIdx.x, lane = tid & 63, w = tid >> 6;
    const int wr = w / WC, wc = w % WC;
    const int lr = lane & 15, lg = lane >> 4;
    const int sw = (lr & 7) << 4;                 // read-side swizzle (bytes)
    const int bm = blockIdx.x * BM, bn = blockIdx.y * BN;
    const int jr = lane >> 3;                     // row within 8-row chunk
    const int scbe = ((((lane & 7) * 16) ^ (jr << 4)) >> 1); // pre-swizzled src col (elems)
    const int nTk = K >> 6;

    f32x4 acc[MR][NR];
#pragma unroll
    for (int i = 0; i < MR; i++)
#pragma unroll
        for (int j = 0; j < NR; j++) acc[i][j] = (f32x4){0.f, 0.f, 0.f, 0.f};

    const u16* aSrc = A + (size_t)bm * K + scbe;
    const u16* bSrc = Bt + (size_t)bn * K + scbe;

#define STAGEP(p_, t_)                                                           \
    {                                                                            \
        _Pragma("unroll") for (int q = 0; q < CAW; q++) {                        \
            int ck = w * CAW + q;                                                \
            gload16(aSrc + (size_t)(ck * 8 + jr) * K + (t_) * 64,                \
                    &lA[p_][ck * 512]);                                          \
        }                                                                        \
        _Pragma("unroll") for (int q = 0; q < CBW; q++) {                        \
            int ck = w * CBW + q;                                                \
            gload16(bSrc + (size_t)(ck * 8 + jr) * K + (t_) * 64,                \
                    &lB[p_][ck * 512]);                                          \
        }                                                                        \
    }

    STAGEP(0, 0);

    for (int t = 0; t < nTk; t++) {
        const int p = t & 1;
        if (t + 1 < nTk) {
            STAGEP(p ^ 1, t + 1);
            if constexpr (NLD == 8)
                asm volatile("s_waitcnt vmcnt(8)" ::: "memory");
            else if constexpr (NLD == 7)
                asm volatile("s_waitcnt vmcnt(7)" ::: "memory");
            else
                asm volatile("s_waitcnt vmcnt(0)" ::: "memory");
        } else {
            asm volatile("s_waitcnt vmcnt(0)" ::: "memory");
        }
        __builtin_amdgcn_s_barrier();
        __builtin_amdgcn_sched_barrier(0);        // keep ds_reads below the barrier

        const char* pa = (const char*)&lA[p][0] + (size_t)(wr * MR * 16) * 128;
        const char* pb = (const char*)&lB[p][0] + (size_t)(wc * NR * 16) * 128;
#pragma unroll
        for (int ks = 0; ks < 2; ks++) {
            bf16x8 bfr[NR];
#pragma unroll
            for (int j = 0; j < NR; j++)
                bfr[j] = *(const bf16x8*)(pb + (j * 16 + lr) * 128 +
                                          ((ks * 64 + lg * 16) ^ sw));
#pragma unroll
            for (int mg = 0; mg < MR; mg += 4) {
                bf16x8 af[4];
#pragma unroll
                for (int i = 0; i < 4; i++)
                    af[i] = *(const bf16x8*)(pa + ((mg + i) * 16 + lr) * 128 +
                                             ((ks * 64 + lg * 16) ^ sw));
                __builtin_amdgcn_s_setprio(1);
#pragma unroll
                for (int i = 0; i < 4; i++)
#pragma unroll
                    for (int j = 0; j < NR; j++)
                        acc[mg + i][j] = __builtin_amdgcn_mfma_f32_16x16x32_bf16(
                            af[i], bfr[j], acc[mg + i][j], 0, 0, 0);
                __builtin_amdgcn_s_setprio(0);
            }
        }
        __builtin_amdgcn_s_barrier();
    }
#undef STAGEP

    const int row0 = bm + wr * MR * 16, col0 = bn + wc * NR * 16;
#pragma unroll
    for (int i = 0; i < MR; i++)
#pragma unroll
        for (int j = 0; j < NR; j++)
#pragma unroll
            for (int r = 0; r < 4; r++) {
                int m = row0 + i * 16 + lg * 4 + r;
                int n = col0 + j * 16 + lr;
                float v = acc[i][j][r];
                if (OUT_BF16)
                    ((u16*)C)[(size_t)m * N + n] = f2bf(v);
                else
                    ((float*)C)[(size_t)m * N + n] = v;
            }
}

// ---------- fused RoPE+RMSNorm on K ONLY (blocks [0,nbRope)) + V transpose ----------
// Q's rope/rms is fused into attn_fwd's Q load.
__global__ __launch_bounds__(256) void rope_trans(u16* __restrict__ qkv,
                                                  const float* __restrict__ cosc,
                                                  const float* __restrict__ sinc,
                                                  const int* __restrict__ pos_ids,
                                                  u16* __restrict__ vT, int S, int nbRope) {
    __shared__ u16 lt[64][72];
    const int bid = blockIdx.x;
    const int tid = threadIdx.x;
    if (bid < nbRope) {
        int idx = bid * 4 + (tid >> 6);      // one wave per (token, head), k only
        int lane = tid & 63;
        int token = idx >> 4;
        int h = idx & 15;
        u16* p = qkv + (size_t)token * 3072 + 1024 + h * 64;
        float x = bf2f(p[lane]);
        float xp = __shfl_xor(x, 32);
        int pos = pos_ids[token];
        int j = lane & 31;
        float c = cosc[pos * 32 + j], s = sinc[pos * 32 + j];
        float y = (lane < 32) ? (x * c + xp * s) : (x * c - xp * s);
        float ss = y * y;
#pragma unroll
        for (int m = 1; m < 64; m <<= 1) ss += __shfl_xor(ss, m);
        float r = rsqrtf(ss * (1.0f / 64.0f) + 1.1920929e-07f);
        p[lane] = f2bf(y * r);
    } else {
        int t = bid - nbRope;
        int nsc = S >> 6;
        int bh = t / nsc;
        int b = bh >> 4, h = bh & 15;
        int s0 = (t - bh * nsc) * 64;
        {
            int s = tid >> 2, dp = (tid & 3) * 16;
            const u16* src = qkv + (size_t)(b * S + s0 + s) * 3072 + 2048 + h * 64 + dp;
            u16x8 v0 = *(const u16x8*)src;
            u16x8 v1 = *(const u16x8*)(src + 8);
#pragma unroll
            for (int i = 0; i < 8; i++) lt[s][dp + i] = v0[i];
#pragma unroll
            for (int i = 0; i < 8; i++) lt[s][dp + 8 + i] = v1[i];
        }
        __syncthreads();
        {
            int d = tid >> 2, sp = (tid & 3) * 16;
            u16x8 o0, o1;
#pragma unroll
            for (int i = 0; i < 8; i++) o0[i] = lt[sp + i][d];
#pragma unroll
            for (int i = 0; i < 8; i++) o1[i] = lt[sp + 8 + i][d];
            u16* dst = vT + ((size_t)bh * 64 + d) * S + s0 + sp;
            *(u16x8*)dst = o0;
            *(u16x8*)(dst + 8) = o1;
        }
    }
}

// ---------------- causal flash attention, balanced-pair + dbuf, base-2 ----------------
// grid (B*H, S/128). Block p handles q-tiles {p, nq-1-p} sequentially -> every
// block does exactly nq+1 kv-steps. Swapped QK^T, lane-local softmax.
// Q RoPE+RMSNorm fused into LOADQ (raw q read from qkv; one bf16 rounding total).
__global__ __launch_bounds__(256) void attn_fwd(const u16* __restrict__ qkv,
                                                const u16* __restrict__ vT,
                                                const float* __restrict__ cosc,
                                                const float* __restrict__ sinc,
                                                u16* __restrict__ out, int S) {
    const int bh = blockIdx.x, b = bh >> 4, h = bh & 15;
    const int tid = threadIdx.x, lane = tid & 63, w = tid >> 6;
    const int lr = lane & 15, lg = lane >> 4;
    const int sw = (lr & 7) << 4;            // read-side XOR swizzle (byte)

    const int nq = S >> 6;
    const int i1 = blockIdx.y;               // light tile
    const int i2 = (nq - 1) - i1;            // heavy tile
    const int n1 = i1 + 1, ntot = n1 + i2 + 1;

    __shared__ u16 lK[2][64 * 64];           // [kv][d], rows 128B, swizzled
    __shared__ u16 lVt[2][64 * 64];          // [d][kv], rows 128B, swizzled
    __shared__ u16 lP[4][16 * 64];           // per wave: P[q][k], swizzled

    const int jr = lane >> 3;                // row within chunk
    const int cbyte = (lane & 7) * 16;
    const int scb = cbyte ^ (jr << 4);       // pre-swizzled source byte col
    const int rowA = w * 16 + jr, rowB = rowA + 8;
    const u16* kSrc = qkv + 1024 + h * 64 + (scb >> 1);
    const u16* vSrc = vT + (size_t)bh * 64 * S + (scb >> 1);

#define STAGE(bufi, kv0_)                                                        \
    {                                                                            \
        const u16* kb = kSrc + (size_t)(b * S + (kv0_)) * 3072;                  \
        const u16* vb = vSrc + (kv0_);                                           \
        gload16(kb + (size_t)rowA * 3072, &lK[bufi][(w * 2) * 512]);             \
        gload16(kb + (size_t)rowB * 3072, &lK[bufi][(w * 2 + 1) * 512]);         \
        gload16(vb + (size_t)rowA * S, &lVt[bufi][(w * 2) * 512]);               \
        gload16(vb + (size_t)rowB * S, &lVt[bufi][(w * 2 + 1) * 512]);           \
    }

    bf16x8 bQ[2];
    f32x4 oT[4];
    float mrun, lrun;

    // LOADQ: read raw q, apply RoPE (pairs d <-> d+32 live in bQ[0]/bQ[1]),
    // RMSNorm (reduce over the 4 lg-groups of this row), then fold in
    // 1/sqrt(64)*log2(e) so softmax runs in base-2 domain.
#define LOADQ(tile_)                                                             \
    {                                                                            \
        const int qrow = (tile_)*64 + w * 16 + lr;                               \
        const u16* qp = qkv + (size_t)(b * S + qrow) * 3072 + h * 64;            \
        u16x8 t0 = *(const u16x8*)(qp + lg * 8);                                 \
        u16x8 t1 = *(const u16x8*)(qp + 32 + lg * 8);                            \
        const float* cc = cosc + qrow * 32 + lg * 8;                             \
        const float* sc = sinc + qrow * 32 + lg * 8;                             \
        float y0[8], y1[8], ss = 0.f;                                            \
        _Pragma("unroll") for (int i = 0; i < 8; i++) {                          \
            float c = cc[i], s = sc[i];                                          \
            float x1 = bf2f(t0[i]), x2 = bf2f(t1[i]);                            \
            y0[i] = x1 * c + x2 * s;                                             \
            y1[i] = x2 * c - x1 * s;                                             \
            ss += y0[i] * y0[i] + y1[i] * y1[i];                                 \
        }                                                                        \
        ss += __shfl_xor(ss, 16);                                                \
        ss += __shfl_xor(ss, 32);                                                \
        float sc2 = rsqrtf(ss * (1.0f / 64.0f) + 1.1920929e-07f) * 0.18033688f;  \
        bf16x8 a0, a1;                                                           \
        _Pragma("unroll") for (int i = 0; i < 8; i++) {                          \
            a0[i] = (__bf16)(y0[i] * sc2);                                       \
            a1[i] = (__bf16)(y1[i] * sc2);                                       \
        }                                                                        \
        bQ[0] = a0; bQ[1] = a1;                                                  \
    }

    STAGE(0, 0);
    LOADQ(i1);
#pragma unroll
    for (int df = 0; df < 4; df++) oT[df] = (f32x4){0.f, 0.f, 0.f, 0.f};
    mrun = -3.0e38f; lrun = 0.f;
    __syncthreads();

    int buf = 0;
    for (int s = 0; s < ntot; s++) {
        const int tile = (s < n1) ? i1 : i2;
        const int kv0 = ((s < n1) ? s : s - n1) * 64;
        if (s + 1 < ntot) {
            int ns = s + 1;
            int nkv0 = ((ns < n1) ? ns : ns - n1) * 64;
            STAGE(buf ^ 1, nkv0);
        }
        const bool diag = (s == n1 - 1) || (s == ntot - 1);

        // ---- QK^T (swapped): S^T[kv][q] ----
        f32x4 st[4];
#pragma unroll
        for (int kf = 0; kf < 4; kf++) {
            const char* kb = (const char*)&lK[buf][0] + (kf * 16 + lr) * 128;
            bf16x8 k0 = *(const bf16x8*)(kb + ((lg * 16) ^ sw));
            bf16x8 k1 = *(const bf16x8*)(kb + ((64 + lg * 16) ^ sw));
            f32x4 z = (f32x4){0.f, 0.f, 0.f, 0.f};
            z = __builtin_amdgcn_mfma_f32_16x16x32_bf16(k0, bQ[0], z, 0, 0, 0);
            st[kf] = __builtin_amdgcn_mfma_f32_16x16x32_bf16(k1, bQ[1], z, 0, 0, 0);
        }

        // ---- mask (diagonal steps only) + lane-local online softmax (base 2) ----
        if (diag) {
            const int qg = tile * 64 + w * 16 + lr;
#pragma unroll
            for (int kf = 0; kf < 4; kf++)
#pragma unroll
                for (int r = 0; r < 4; r++) {
                    int kvg = kv0 + kf * 16 + lg * 4 + r;
                    if (kvg > qg) st[kf][r] = -3.0e38f;
                }
        }
        float mx = -3.0e38f;
#pragma unroll
        for (int kf = 0; kf < 4; kf++) {
            float mk = fmaxf(fmaxf(st[kf][0], st[kf][1]), fmaxf(st[kf][2], st[kf][3]));
            mx = fmaxf(mx, mk);
        }
        mx = fmaxf(mx, __shfl_xor(mx, 16));
        mx = fmaxf(mx, __shfl_xor(mx, 32));
        if (!__all(mx <= mrun + 11.54f)) {    // T13 defer-max (log2 domain)
            float mnew = fmaxf(mrun, mx);
            float alpha = exp2f(mrun - mnew);
            mrun = mnew;
            lrun *= alpha;
#pragma unroll
            for (int df = 0; df < 4; df++)
#pragma unroll
                for (int r = 0; r < 4; r++) oT[df][r] *= alpha;
        }
        float ps = 0.f;
#pragma unroll
        for (int kf = 0; kf < 4; kf++)
#pragma unroll
            for (int r = 0; r < 4; r++) {
                float p = exp2f(st[kf][r] - mrun);
                st[kf][r] = p;
                ps += p;
            }
        ps += __shfl_xor(ps, 16);
        ps += __shfl_xor(ps, 32);
        lrun += ps;

        // ---- P -> LDS (bf16, swizzled rows of 128B) ----
        {
            char* pb = (char*)&lP[w][0] + lr * 128;
#pragma unroll
            for (int kf = 0; kf < 4; kf++) {
                uint2 pk;
                pk.x = cvt_pk_bf16(st[kf][0], st[kf][1]);
                pk.y = cvt_pk_bf16(st[kf][2], st[kf][3]);
                *(uint2*)(pb + ((kf * 32 + lg * 8) ^ sw)) = pk;
            }
        }

        // ---- PV (swapped): O^T += Vt . P^T ----
#pragma unroll
        for (int kc = 0; kc < 2; kc++) {
            bf16x8 bp = *(const bf16x8*)((const char*)&lP[w][0] + lr * 128 +
                                         ((kc * 64 + lg * 16) ^ sw));
#pragma unroll
            for (int df = 0; df < 4; df++) {
                bf16x8 av = *(const bf16x8*)((const char*)&lVt[buf][0] +
                                             (df * 16 + lr) * 128 +
                                             ((kc * 64 + lg * 16) ^ sw));
                oT[df] = __builtin_amdgcn_mfma_f32_16x16x32_bf16(av, bp, oT[df], 0, 0, 0);
            }
        }

        if (diag) {
            float inv = 1.0f / lrun;
            u16* op = out + (size_t)(b * S + tile * 64 + w * 16 + lr) * 1024 +
                      h * 64 + lg * 4;
#pragma unroll
            for (int df = 0; df < 4; df++) {
                u16x4 o;
#pragma unroll
                for (int r = 0; r < 4; r++) o[r] = f2bf(oT[df][r] * inv);
                *(u16x4*)(op + df * 16) = o;
            }
            if (s != ntot - 1) {              // switch to heavy tile
                LOADQ(i2);
#pragma unroll
                for (int df = 0; df < 4; df++) oT[df] = (f32x4){0.f, 0.f, 0.f, 0.f};
                mrun = -3.0e38f; lrun = 0.f;
            }
        }
        __syncthreads();
        buf ^= 1;
    }
#undef STAGE
#undef LOADQ
}

extern "C" void kernel_launch(void* const* d_in, const int* in_sizes, int n_in,
                              void* d_out, int out_size, void* d_ws, size_t ws_size,
                              hipStream_t stream) {
    const float* x     = (const float*)d_in[0];
    const float* Wqkv  = (const float*)d_in[1];
    const float* Wo    = (const float*)d_in[2];
    const float* cosc  = (const float*)d_in[3];
    const float* sinc  = (const float*)d_in[4];
    const int* pos_ids = (const int*)d_in[6];

    const int E = 1024, H = 16;
    int S = in_sizes[3] / 32;       // cos_cache is S x 32
    int N = in_sizes[0] / E;
    int B = N / S;

    char* ws = (char*)d_ws;
    u16* xb    = (u16*)ws;                                          // N*E bf16 (reused as attn out)
    u16* wqkvb = (u16*)(ws + (size_t)N * E * 2);                    // 3E*E
    u16* wob   = (u16*)(ws + (size_t)N * E * 2 + (size_t)3 * E * E * 2);
    u16* qkvb  = (u16*)(ws + (size_t)N * E * 2 + (size_t)4 * E * E * 2);
    u16* vTb   = (u16*)(ws + (size_t)N * E * 2 + (size_t)4 * E * E * 2 + (size_t)N * 3 * E * 2);
    u16* aout  = xb;

    // one fused convert: dest segments xb|wqkvb|wob are contiguous in ws
    int n0 = N * E, n1 = 3 * E * E, n2 = E * E;
    cvt_all<<<(n0 + n1 + n2) / 1024, 256, 0, stream>>>(x, Wqkv, Wo, xb, n0, n1);

    // qkv GEMM: 256x192 tiles -> grid 16x16 = 256 blocks (exact CU fill)
    gemm_pipe<256, 192, 2, 4, true><<<dim3(N / 256, 3 * E / 192), 512, 0, stream>>>(
        xb, wqkvb, qkvb, N, 3 * E, E);

    // fused RoPE+RMS (K only; Q fused into attn) + V transpose
    int nbRope = N * H / 4;
    int nbTrans = B * H * (S / 64);
    rope_trans<<<nbRope + nbTrans, 256, 0, stream>>>(qkvb, cosc, sinc, pos_ids, vTb, S, nbRope);

    // attention: balanced-pair blocks, grid (B*H, S/128), fused Q rope/rms
    attn_fwd<<<dim3(B * H, S / 128), 256, 0, stream>>>(qkvb, vTb, cosc, sinc, aout, S);

    // out GEMM: 128x128 tiles -> grid 32x8 = 256 blocks
    gemm_pipe<128, 128, 2, 2, false><<<dim3(N / 128, E / 128), 256, 0, stream>>>(
        aout, wob, d_out, N, E, E);
}

// Round 10
// 104.509 us; speedup vs baseline: 1.1695x; 1.0667x over previous
//
#include <hip/hip_runtime.h>
#include <hip/hip_bf16.h>

typedef unsigned short u16;
typedef __bf16 bf16x8 __attribute__((ext_vector_type(8)));
typedef float f32x4 __attribute__((ext_vector_type(4)));
typedef u16 u16x8 __attribute__((ext_vector_type(8)));
typedef u16 u16x4 __attribute__((ext_vector_type(4)));

__device__ __forceinline__ u16 f2bf(float f) {
    unsigned u = __builtin_bit_cast(unsigned, f);
    unsigned r = u + 0x7FFFu + ((u >> 16) & 1u);
    return (u16)(r >> 16);
}
__device__ __forceinline__ float bf2f(u16 h) {
    return __builtin_bit_cast(float, (unsigned)h << 16);
}
__device__ __forceinline__ unsigned cvt_pk_bf16(float lo, float hi) {
    unsigned r;
    asm("v_cvt_pk_bf16_f32 %0, %1, %2" : "=v"(r) : "v"(lo), "v"(hi));
    return r;
}
__device__ __forceinline__ void gload16(const void* g, void* l) {
    __builtin_amdgcn_global_load_lds((const __attribute__((address_space(1))) void*)g,
                                     (__attribute__((address_space(3))) void*)l, 16, 0, 0);
}

// ---------- fused fp32 -> bf16 convert of x | Wqkv | Wo into contiguous ws ----------
__global__ __launch_bounds__(256) void cvt_all(const float* __restrict__ x,
                                               const float* __restrict__ wqkv,
                                               const float* __restrict__ wo,
                                               u16* __restrict__ dst, int n0, int n1) {
    int i = (blockIdx.x * 256 + threadIdx.x) * 4;
    const float* src;
    if (i < n0)            src = x + i;
    else if (i < n0 + n1)  src = wqkv + (i - n0);
    else                   src = wo + (i - n0 - n1);
    float4 v = *(const float4*)src;
    u16x4 o;
    o[0] = f2bf(v.x); o[1] = f2bf(v.y); o[2] = f2bf(v.z); o[3] = f2bf(v.w);
    *(u16x4*)(dst + i) = o;
}

// ------------- deep-pipelined bf16 GEMM: C[M][N] = A[M][K] * Bt[N][K]^T -------------
// BK=64, double-buffered LDS, counted vmcnt (prefetch next tile in flight across
// compute), XOR-swizzled tiles (byte ^= (row&7)<<4) via pre-swizzled source.
// Tiles sized for >=2 blocks/CU: independent blocks cover each other's HBM-latency
// stalls (m103: 128^2 @ multi-block/CU beats 256^2 @ 1 block/CU in this structure).
template <int BM, int BN, int WR, int WC, bool OUT_BF16>
__global__ __launch_bounds__(WR * WC * 64, 2) void gemm_pipe(const u16* __restrict__ A,
                                                             const u16* __restrict__ Bt,
                                                             void* __restrict__ C,
                                                             int M, int N, int K) {
    constexpr int NW = WR * WC;
    constexpr int MR = BM / WR / 16, NR = BN / WC / 16;
    constexpr int MGS = (MR >= 4) ? 4 : MR;       // MFMA group rows
    constexpr int CA = BM / 8, CB = BN / 8;       // 1KB staging chunks (8 rows x 128B)
    constexpr int CAW = CA / NW, CBW = CB / NW;   // chunks per wave
    constexpr int NLD = CAW + CBW;                // gloads per thread per tile

    __shared__ u16 lA[2][BM * 64];
    __shared__ u16 lB[2][BN * 64];

    const int tid = threadIdx.x, lane = tid & 63, w = tid >> 6;
    const int wr = w / WC, wc = w % WC;
    const int lr = lane & 15, lg = lane >> 4;
    const int sw = (lr & 7) << 4;                 // read-side swizzle (bytes)
    const int bm = blockIdx.x * BM, bn = blockIdx.y * BN;
    const int jr = lane >> 3;                     // row within 8-row chunk
    const int scbe = ((((lane & 7) * 16) ^ (jr << 4)) >> 1); // pre-swizzled src col (elems)
    const int nTk = K >> 6;

    f32x4 acc[MR][NR];
#pragma unroll
    for (int i = 0; i < MR; i++)
#pragma unroll
        for (int j = 0; j < NR; j++) acc[i][j] = (f32x4){0.f, 0.f, 0.f, 0.f};

    const u16* aSrc = A + (size_t)bm * K + scbe;
    const u16* bSrc = Bt + (size_t)bn * K + scbe;

#define STAGEP(p_, t_)                                                           \
    {                                                                            \
        _Pragma("unroll") for (int q = 0; q < CAW; q++) {                        \
            int ck = w * CAW + q;                                                \
            gload16(aSrc + (size_t)(ck * 8 + jr) * K + (t_) * 64,                \
                    &lA[p_][ck * 512]);                                          \
        }                                                                        \
        _Pragma("unroll") for (int q = 0; q < CBW; q++) {                        \
            int ck = w * CBW + q;                                                \
            gload16(bSrc + (size_t)(ck * 8 + jr) * K + (t_) * 64,                \
                    &lB[p_][ck * 512]);                                          \
        }                                                                        \
    }

    STAGEP(0, 0);

    for (int t = 0; t < nTk; t++) {
        const int p = t & 1;
        if (t + 1 < nTk) {
            STAGEP(p ^ 1, t + 1);
            if constexpr (NLD == 6)
                asm volatile("s_waitcnt vmcnt(6)" ::: "memory");
            else if constexpr (NLD == 7)
                asm volatile("s_waitcnt vmcnt(7)" ::: "memory");
            else if constexpr (NLD == 8)
                asm volatile("s_waitcnt vmcnt(8)" ::: "memory");
            else if constexpr (NLD == 10)
                asm volatile("s_waitcnt vmcnt(10)" ::: "memory");
            else
                asm volatile("s_waitcnt vmcnt(0)" ::: "memory");
        } else {
            asm volatile("s_waitcnt vmcnt(0)" ::: "memory");
        }
        __builtin_amdgcn_s_barrier();
        __builtin_amdgcn_sched_barrier(0);        // keep ds_reads below the barrier

        const char* pa = (const char*)&lA[p][0] + (size_t)(wr * MR * 16) * 128;
        const char* pb = (const char*)&lB[p][0] + (size_t)(wc * NR * 16) * 128;
#pragma unroll
        for (int ks = 0; ks < 2; ks++) {
            bf16x8 bfr[NR];
#pragma unroll
            for (int j = 0; j < NR; j++)
                bfr[j] = *(const bf16x8*)(pb + (j * 16 + lr) * 128 +
                                          ((ks * 64 + lg * 16) ^ sw));
#pragma unroll
            for (int mg = 0; mg < MR; mg += MGS) {
                bf16x8 af[MGS];
#pragma unroll
                for (int i = 0; i < MGS; i++)
                    af[i] = *(const bf16x8*)(pa + ((mg + i) * 16 + lr) * 128 +
                                             ((ks * 64 + lg * 16) ^ sw));
                __builtin_amdgcn_s_setprio(1);
#pragma unroll
                for (int i = 0; i < MGS; i++)
#pragma unroll
                    for (int j = 0; j < NR; j++)
                        acc[mg + i][j] = __builtin_amdgcn_mfma_f32_16x16x32_bf16(
                            af[i], bfr[j], acc[mg + i][j], 0, 0, 0);
                __builtin_amdgcn_s_setprio(0);
            }
        }
        __builtin_amdgcn_s_barrier();
    }
#undef STAGEP

    const int row0 = bm + wr * MR * 16, col0 = bn + wc * NR * 16;
#pragma unroll
    for (int i = 0; i < MR; i++)
#pragma unroll
        for (int j = 0; j < NR; j++)
#pragma unroll
            for (int r = 0; r < 4; r++) {
                int m = row0 + i * 16 + lg * 4 + r;
                int n = col0 + j * 16 + lr;
                float v = acc[i][j][r];
                if (OUT_BF16)
                    ((u16*)C)[(size_t)m * N + n] = f2bf(v);
                else
                    ((float*)C)[(size_t)m * N + n] = v;
            }
}

// ---------- fused RoPE+RMSNorm on K ONLY (blocks [0,nbRope)) + V transpose ----------
// Q's rope/rms is fused into attn_fwd's Q load.
__global__ __launch_bounds__(256) void rope_trans(u16* __restrict__ qkv,
                                                  const float* __restrict__ cosc,
                                                  const float* __restrict__ sinc,
                                                  const int* __restrict__ pos_ids,
                                                  u16* __restrict__ vT, int S, int nbRope) {
    __shared__ u16 lt[64][72];
    const int bid = blockIdx.x;
    const int tid = threadIdx.x;
    if (bid < nbRope) {
        int idx = bid * 4 + (tid >> 6);      // one wave per (token, head), k only
        int lane = tid & 63;
        int token = idx >> 4;
        int h = idx & 15;
        u16* p = qkv + (size_t)token * 3072 + 1024 + h * 64;
        float x = bf2f(p[lane]);
        float xp = __shfl_xor(x, 32);
        int pos = pos_ids[token];
        int j = lane & 31;
        float c = cosc[pos * 32 + j], s = sinc[pos * 32 + j];
        float y = (lane < 32) ? (x * c + xp * s) : (x * c - xp * s);
        float ss = y * y;
#pragma unroll
        for (int m = 1; m < 64; m <<= 1) ss += __shfl_xor(ss, m);
        float r = rsqrtf(ss * (1.0f / 64.0f) + 1.1920929e-07f);
        p[lane] = f2bf(y * r);
    } else {
        int t = bid - nbRope;
        int nsc = S >> 6;
        int bh = t / nsc;
        int b = bh >> 4, h = bh & 15;
        int s0 = (t - bh * nsc) * 64;
        {
            int s = tid >> 2, dp = (tid & 3) * 16;
            const u16* src = qkv + (size_t)(b * S + s0 + s) * 3072 + 2048 + h * 64 + dp;
            u16x8 v0 = *(const u16x8*)src;
            u16x8 v1 = *(const u16x8*)(src + 8);
#pragma unroll
            for (int i = 0; i < 8; i++) lt[s][dp + i] = v0[i];
#pragma unroll
            for (int i = 0; i < 8; i++) lt[s][dp + 8 + i] = v1[i];
        }
        __syncthreads();
        {
            int d = tid >> 2, sp = (tid & 3) * 16;
            u16x8 o0, o1;
#pragma unroll
            for (int i = 0; i < 8; i++) o0[i] = lt[sp + i][d];
#pragma unroll
            for (int i = 0; i < 8; i++) o1[i] = lt[sp + 8 + i][d];
            u16* dst = vT + ((size_t)bh * 64 + d) * S + s0 + sp;
            *(u16x8*)dst = o0;
            *(u16x8*)(dst + 8) = o1;
        }
    }
}

// ---------------- causal flash attention, balanced-pair + dbuf, base-2 ----------------
// grid (B*H, S/128). Block p handles q-tiles {p, nq-1-p} sequentially -> every
// block does exactly nq+1 kv-steps. Swapped QK^T, lane-local softmax.
// Q RoPE+RMSNorm fused into LOADQ (raw q read from qkv; one bf16 rounding total).
__global__ __launch_bounds__(256) void attn_fwd(const u16* __restrict__ qkv,
                                                const u16* __restrict__ vT,
                                                const float* __restrict__ cosc,
                                                const float* __restrict__ sinc,
                                                u16* __restrict__ out, int S) {
    const int bh = blockIdx.x, b = bh >> 4, h = bh & 15;
    const int tid = threadIdx.x, lane = tid & 63, w = tid >> 6;
    const int lr = lane & 15, lg = lane >> 4;
    const int sw = (lr & 7) << 4;            // read-side XOR swizzle (byte)

    const int nq = S >> 6;
    const int i1 = blockIdx.y;               // light tile
    const int i2 = (nq - 1) - i1;            // heavy tile
    const int n1 = i1 + 1, ntot = n1 + i2 + 1;

    __shared__ u16 lK[2][64 * 64];           // [kv][d], rows 128B, swizzled
    __shared__ u16 lVt[2][64 * 64];          // [d][kv], rows 128B, swizzled
    __shared__ u16 lP[4][16 * 64];           // per wave: P[q][k], swizzled

    const int jr = lane >> 3;                // row within chunk
    const int cbyte = (lane & 7) * 16;
    const int scb = cbyte ^ (jr << 4);       // pre-swizzled source byte col
    const int rowA = w * 16 + jr, rowB = rowA + 8;
    const u16* kSrc = qkv + 1024 + h * 64 + (scb >> 1);
    const u16* vSrc = vT + (size_t)bh * 64 * S + (scb >> 1);

#define STAGE(bufi, kv0_)                                                        \
    {                                                                            \
        const u16* kb = kSrc + (size_t)(b * S + (kv0_)) * 3072;                  \
        const u16* vb = vSrc + (kv0_);                                           \
        gload16(kb + (size_t)rowA * 3072, &lK[bufi][(w * 2) * 512]);             \
        gload16(kb + (size_t)rowB * 3072, &lK[bufi][(w * 2 + 1) * 512]);         \
        gload16(vb + (size_t)rowA * S, &lVt[bufi][(w * 2) * 512]);               \
        gload16(vb + (size_t)rowB * S, &lVt[bufi][(w * 2 + 1) * 512]);           \
    }

    bf16x8 bQ[2];
    f32x4 oT[4];
    float mrun, lrun;

    // LOADQ: read raw q, apply RoPE (pairs d <-> d+32 live in bQ[0]/bQ[1]),
    // RMSNorm (reduce over the 4 lg-groups of this row), then fold in
    // 1/sqrt(64)*log2(e) so softmax runs in base-2 domain.
#define LOADQ(tile_)                                                             \
    {                                                                            \
        const int qrow = (tile_)*64 + w * 16 + lr;                               \
        const u16* qp = qkv + (size_t)(b * S + qrow) * 3072 + h * 64;            \
        u16x8 t0 = *(const u16x8*)(qp + lg * 8);                                 \
        u16x8 t1 = *(const u16x8*)(qp + 32 + lg * 8);                            \
        const float* cc = cosc + qrow * 32 + lg * 8;                             \
        const float* sc = sinc + qrow * 32 + lg * 8;                             \
        float y0[8], y1[8], ss = 0.f;                                            \
        _Pragma("unroll") for (int i = 0; i < 8; i++) {                          \
            float c = cc[i], s = sc[i];                                          \
            float x1 = bf2f(t0[i]), x2 = bf2f(t1[i]);                            \
            y0[i] = x1 * c + x2 * s;                                             \
            y1[i] = x2 * c - x1 * s;                                             \
            ss += y0[i] * y0[i] + y1[i] * y1[i];                                 \
        }                                                                        \
        ss += __shfl_xor(ss, 16);                                                \
        ss += __shfl_xor(ss, 32);                                                \
        float sc2 = rsqrtf(ss * (1.0f / 64.0f) + 1.1920929e-07f) * 0.18033688f;  \
        bf16x8 a0, a1;                                                           \
        _Pragma("unroll") for (int i = 0; i < 8; i++) {                          \
            a0[i] = (__bf16)(y0[i] * sc2);                                       \
            a1[i] = (__bf16)(y1[i] * sc2);                                       \
        }                                                                        \
        bQ[0] = a0; bQ[1] = a1;                                                  \
    }

    STAGE(0, 0);
    LOADQ(i1);
#pragma unroll
    for (int df = 0; df < 4; df++) oT[df] = (f32x4){0.f, 0.f, 0.f, 0.f};
    mrun = -3.0e38f; lrun = 0.f;
    __syncthreads();

    int buf = 0;
    for (int s = 0; s < ntot; s++) {
        const int tile = (s < n1) ? i1 : i2;
        const int kv0 = ((s < n1) ? s : s - n1) * 64;
        if (s + 1 < ntot) {
            int ns = s + 1;
            int nkv0 = ((ns < n1) ? ns : ns - n1) * 64;
            STAGE(buf ^ 1, nkv0);
        }
        const bool diag = (s == n1 - 1) || (s == ntot - 1);

        // ---- QK^T (swapped): S^T[kv][q] ----
        f32x4 st[4];
#pragma unroll
        for (int kf = 0; kf < 4; kf++) {
            const char* kb = (const char*)&lK[buf][0] + (kf * 16 + lr) * 128;
            bf16x8 k0 = *(const bf16x8*)(kb + ((lg * 16) ^ sw));
            bf16x8 k1 = *(const bf16x8*)(kb + ((64 + lg * 16) ^ sw));
            f32x4 z = (f32x4){0.f, 0.f, 0.f, 0.f};
            z = __builtin_amdgcn_mfma_f32_16x16x32_bf16(k0, bQ[0], z, 0, 0, 0);
            st[kf] = __builtin_amdgcn_mfma_f32_16x16x32_bf16(k1, bQ[1], z, 0, 0, 0);
        }

        // ---- mask (diagonal steps only) + lane-local online softmax (base 2) ----
        if (diag) {
            const int qg = tile * 64 + w * 16 + lr;
#pragma unroll
            for (int kf = 0; kf < 4; kf++)
#pragma unroll
                for (int r = 0; r < 4; r++) {
                    int kvg = kv0 + kf * 16 + lg * 4 + r;
                    if (kvg > qg) st[kf][r] = -3.0e38f;
                }
        }
        float mx = -3.0e38f;
#pragma unroll
        for (int kf = 0; kf < 4; kf++) {
            float mk = fmaxf(fmaxf(st[kf][0], st[kf][1]), fmaxf(st[kf][2], st[kf][3]));
            mx = fmaxf(mx, mk);
        }
        mx = fmaxf(mx, __shfl_xor(mx, 16));
        mx = fmaxf(mx, __shfl_xor(mx, 32));
        if (!__all(mx <= mrun + 11.54f)) {    // T13 defer-max (log2 domain)
            float mnew = fmaxf(mrun, mx);
            float alpha = exp2f(mrun - mnew);
            mrun = mnew;
            lrun *= alpha;
#pragma unroll
            for (int df = 0; df < 4; df++)
#pragma unroll
                for (int r = 0; r < 4; r++) oT[df][r] *= alpha;
        }
        float ps = 0.f;
#pragma unroll
        for (int kf = 0; kf < 4; kf++)
#pragma unroll
            for (int r = 0; r < 4; r++) {
                float p = exp2f(st[kf][r] - mrun);
                st[kf][r] = p;
                ps += p;
            }
        ps += __shfl_xor(ps, 16);
        ps += __shfl_xor(ps, 32);
        lrun += ps;

        // ---- P -> LDS (bf16, swizzled rows of 128B) ----
        {
            char* pb = (char*)&lP[w][0] + lr * 128;
#pragma unroll
            for (int kf = 0; kf < 4; kf++) {
                uint2 pk;
                pk.x = cvt_pk_bf16(st[kf][0], st[kf][1]);
                pk.y = cvt_pk_bf16(st[kf][2], st[kf][3]);
                *(uint2*)(pb + ((kf * 32 + lg * 8) ^ sw)) = pk;
            }
        }

        // ---- PV (swapped): O^T += Vt . P^T ----
#pragma unroll
        for (int kc = 0; kc < 2; kc++) {
            bf16x8 bp = *(const bf16x8*)((const char*)&lP[w][0] + lr * 128 +
                                         ((kc * 64 + lg * 16) ^ sw));
#pragma unroll
            for (int df = 0; df < 4; df++) {
                bf16x8 av = *(const bf16x8*)((const char*)&lVt[buf][0] +
                                             (df * 16 + lr) * 128 +
                                             ((kc * 64 + lg * 16) ^ sw));
                oT[df] = __builtin_amdgcn_mfma_f32_16x16x32_bf16(av, bp, oT[df], 0, 0, 0);
            }
        }

        if (diag) {
            float inv = 1.0f / lrun;
            u16* op = out + (size_t)(b * S + tile * 64 + w * 16 + lr) * 1024 +
                      h * 64 + lg * 4;
#pragma unroll
            for (int df = 0; df < 4; df++) {
                u16x4 o;
#pragma unroll
                for (int r = 0; r < 4; r++) o[r] = f2bf(oT[df][r] * inv);
                *(u16x4*)(op + df * 16) = o;
            }
            if (s != ntot - 1) {              // switch to heavy tile
                LOADQ(i2);
#pragma unroll
                for (int df = 0; df < 4; df++) oT[df] = (f32x4){0.f, 0.f, 0.f, 0.f};
                mrun = -3.0e38f; lrun = 0.f;
            }
        }
        __syncthreads();
        buf ^= 1;
    }
#undef STAGE
#undef LOADQ
}

extern "C" void kernel_launch(void* const* d_in, const int* in_sizes, int n_in,
                              void* d_out, int out_size, void* d_ws, size_t ws_size,
                              hipStream_t stream) {
    const float* x     = (const float*)d_in[0];
    const float* Wqkv  = (const float*)d_in[1];
    const float* Wo    = (const float*)d_in[2];
    const float* cosc  = (const float*)d_in[3];
    const float* sinc  = (const float*)d_in[4];
    const int* pos_ids = (const int*)d_in[6];

    const int E = 1024, H = 16;
    int S = in_sizes[3] / 32;       // cos_cache is S x 32
    int N = in_sizes[0] / E;
    int B = N / S;

    char* ws = (char*)d_ws;
    u16* xb    = (u16*)ws;                                          // N*E bf16 (reused as attn out)
    u16* wqkvb = (u16*)(ws + (size_t)N * E * 2);                    // 3E*E
    u16* wob   = (u16*)(ws + (size_t)N * E * 2 + (size_t)3 * E * E * 2);
    u16* qkvb  = (u16*)(ws + (size_t)N * E * 2 + (size_t)4 * E * E * 2);
    u16* vTb   = (u16*)(ws + (size_t)N * E * 2 + (size_t)4 * E * E * 2 + (size_t)N * 3 * E * 2);
    u16* aout  = xb;

    // one fused convert: dest segments xb|wqkvb|wob are contiguous in ws
    int n0 = N * E, n1 = 3 * E * E, n2 = E * E;
    cvt_all<<<(n0 + n1 + n2) / 1024, 256, 0, stream>>>(x, Wqkv, Wo, xb, n0, n1);

    // qkv GEMM: 128x192 tiles, 80KB LDS -> 2 blocks/CU; grid 32x16 = 512 = 2/CU
    gemm_pipe<128, 192, 2, 2, true><<<dim3(N / 128, 3 * E / 192), 256, 0, stream>>>(
        xb, wqkvb, qkvb, N, 3 * E, E);

    // fused RoPE+RMS (K only; Q fused into attn) + V transpose
    int nbRope = N * H / 4;
    int nbTrans = B * H * (S / 64);
    rope_trans<<<nbRope + nbTrans, 256, 0, stream>>>(qkvb, cosc, sinc, pos_ids, vTb, S, nbRope);

    // attention: balanced-pair blocks, grid (B*H, S/128), fused Q rope/rms
    attn_fwd<<<dim3(B * H, S / 128), 256, 0, stream>>>(qkvb, vTb, cosc, sinc, aout, S);

    // out GEMM: 64x128 tiles -> grid 64x8 = 512 = 2 blocks/CU
    gemm_pipe<64, 128, 2, 2, false><<<dim3(N / 64, E / 128), 256, 0, stream>>>(
        aout, wob, d_out, N, E, E);
}